// Round 1
// baseline (95.541 us; speedup 1.0000x reference)
//
#include <hip/hip_runtime.h>
#include <hip/hip_bf16.h>

// Problem constants (N, M, D, A) = (10000, 32, 256, 128)
#define NROW 10000
#define MANC 32
#define DIM  256
#define ADIM 128

typedef __attribute__((ext_vector_type(8))) short short8;
typedef __attribute__((ext_vector_type(4))) short short4v;
typedef __attribute__((ext_vector_type(4))) float floatx4;

__device__ __forceinline__ short f2bf(float x) {
    union { __hip_bfloat16 h; short s; } u;
    u.h = __float2bfloat16(x);
    return u.s;
}
__device__ __forceinline__ float bf2f(unsigned short u) {
    unsigned int x = ((unsigned int)u) << 16;
    return __uint_as_float(x);
}

// ---------------------------------------------------------------------------
// Kernel 1: SP[n][j] = be[n] . W2[j], j<128 -> Wp_self row j, j>=128 -> Wp_anc row j-128
// SP stored bf16. M=10000=625*16 tiles of 16, N=256=16 tiles of 16, K=256.
// One wave per 16x16 output tile, mfma_f32_16x16x32_bf16, 8 K-steps.
// ---------------------------------------------------------------------------
__global__ __launch_bounds__(256) void proj_kernel(
    const float* __restrict__ be, const float* __restrict__ Wp,
    __hip_bfloat16* __restrict__ SP) {
    int wid  = (blockIdx.x * 256 + threadIdx.x) >> 6;   // 0..9999
    int lane = threadIdx.x & 63;
    int tm = wid >> 4;          // 0..624
    int tn = wid & 15;          // 0..15
    int arow = tm * 16 + (lane & 15);
    int bcol = tn * 16 + (lane & 15);
    int kb   = (lane >> 4) * 8;

    const float* asrc = be + arow * DIM;
    // B[k][j] = W2[j][k]:  j<128: Wp[j][k] ; j>=128: Wp[j-128][256+k]
    const float* bsrc = (bcol < ADIM) ? (Wp + bcol * (2 * DIM))
                                      : (Wp + (bcol - ADIM) * (2 * DIM) + DIM);
    floatx4 acc = {0.f, 0.f, 0.f, 0.f};
    for (int k0 = 0; k0 < DIM; k0 += 32) {
        const float* ap = asrc + k0 + kb;
        const float* bq = bsrc + k0 + kb;
        short8 af, bfv;
#pragma unroll
        for (int e = 0; e < 8; ++e) { af[e] = f2bf(ap[e]); bfv[e] = f2bf(bq[e]); }
        acc = __builtin_amdgcn_mfma_f32_16x16x32_bf16(af, bfv, acc, 0, 0, 0);
    }
    // C/D layout (measured m89): col = lane&15, row = (lane>>4)*4 + r
    int orow = tm * 16 + (lane >> 4) * 4;
    int ocol = tn * 16 + (lane & 15);
#pragma unroll
    for (int r = 0; r < 4; ++r) {
        union { __hip_bfloat16 h; short s; } u;
        u.s = f2bf(acc[r]);
        SP[(orow + r) * 256 + ocol] = u.h;
    }
}

// ---------------------------------------------------------------------------
// Kernel 2: bf16 copy of basic_embeddings (halves gather traffic in kernel 3)
// 2,560,000 elements, 640,000 threads x 4 elems.
// ---------------------------------------------------------------------------
__global__ __launch_bounds__(256) void cvt_kernel(
    const float* __restrict__ in, __hip_bfloat16* __restrict__ outb) {
    int tid  = blockIdx.x * 256 + threadIdx.x;
    int base = tid * 4;
    floatx4 v = *reinterpret_cast<const floatx4*>(in + base);
    short4v s;
#pragma unroll
    for (int e = 0; e < 4; ++e) s[e] = f2bf(v[e]);
    *reinterpret_cast<short4v*>(reinterpret_cast<short*>(outb) + base) = s;
}

// ---------------------------------------------------------------------------
// Kernel 3: attention. One wave per row n.
//  lane l owns a = {2l, 2l+1} of the A=128 dim, and d = {4l..4l+3} of D=256.
// ---------------------------------------------------------------------------
__global__ __launch_bounds__(256) void attn_kernel(
    const int*   __restrict__ anc,
    const float* __restrict__ mask,
    const float* __restrict__ bias,
    const float* __restrict__ Ww,
    const __hip_bfloat16* __restrict__ SP,
    const __hip_bfloat16* __restrict__ beb,
    float* __restrict__ out) {
    int n    = (blockIdx.x * 256 + threadIdx.x) >> 6;  // 0..9999
    int lane = threadIdx.x & 63;

    const unsigned short* SPu = reinterpret_cast<const unsigned short*>(SP);

    // self part + bias (wave-uniform row n, coalesced 4B/lane)
    unsigned int sv = *reinterpret_cast<const unsigned int*>(SPu + n * 256 + 2 * lane);
    float ssb0 = bf2f((unsigned short)(sv & 0xffff))  + bias[2 * lane];
    float ssb1 = bf2f((unsigned short)(sv >> 16))     + bias[2 * lane + 1];
    float ww0 = Ww[2 * lane], ww1 = Ww[2 * lane + 1];

    float att[MANC];
#pragma unroll
    for (int m = 0; m < MANC; ++m) {
        int j = anc[n * MANC + m];
        unsigned int pv = *reinterpret_cast<const unsigned int*>(SPu + j * 256 + 128 + 2 * lane);
        float x0 = ssb0 + bf2f((unsigned short)(pv & 0xffff));
        float x1 = ssb1 + bf2f((unsigned short)(pv >> 16));
        x0 = fminf(fmaxf(x0, -15.f), 15.f);
        x1 = fminf(fmaxf(x1, -15.f), 15.f);
        float e0 = __expf(2.f * x0), e1 = __expf(2.f * x1);
        float h0 = 1.f - __fdividef(2.f, e0 + 1.f);
        float h1 = 1.f - __fdividef(2.f, e1 + 1.f);
        float part = h0 * ww0 + h1 * ww1;
#pragma unroll
        for (int off = 1; off < 64; off <<= 1)
            part += __shfl_xor(part, off, 64);
        att[m] = part * mask[n * MANC + m];
    }
    float mx = att[0];
#pragma unroll
    for (int m = 1; m < MANC; ++m) mx = fmaxf(mx, att[m]);
    float wsum = 0.f;
#pragma unroll
    for (int m = 0; m < MANC; ++m) { att[m] = __expf(att[m] - mx); wsum += att[m]; }
    float inv = 1.f / wsum;

    floatx4 acc = {0.f, 0.f, 0.f, 0.f};
#pragma unroll
    for (int m = 0; m < MANC; ++m) {
        int j = anc[n * MANC + m];
        short4v ev = *reinterpret_cast<const short4v*>(
            reinterpret_cast<const short*>(beb) + j * 256 + 4 * lane);
        float wm = att[m];
#pragma unroll
        for (int e = 0; e < 4; ++e)
            acc[e] += wm * bf2f((unsigned short)ev[e]);
    }
    floatx4 r = {acc[0] * inv, acc[1] * inv, acc[2] * inv, acc[3] * inv};
    *reinterpret_cast<floatx4*>(out + n * 256 + 4 * lane) = r;
}

// ---------------------------------------------------------------------------
extern "C" void kernel_launch(void* const* d_in, const int* in_sizes, int n_in,
                              void* d_out, int out_size, void* d_ws, size_t ws_size,
                              hipStream_t stream) {
    const float* be   = (const float*)d_in[0];
    const int*   anc  = (const int*)d_in[1];
    const float* mask = (const float*)d_in[2];
    const float* Wp   = (const float*)d_in[3];
    const float* bias = (const float*)d_in[4];
    const float* Ww   = (const float*)d_in[5];
    float* out = (float*)d_out;

    // ws layout: [0, 5.12MB) SP bf16 (10000x256), [5.12MB, 10.24MB) be bf16
    __hip_bfloat16* SPb = (__hip_bfloat16*)d_ws;
    __hip_bfloat16* beb = (__hip_bfloat16*)((char*)d_ws + (size_t)NROW * 256 * 2);

    // 10000 waves = 2500 blocks x 4 waves for kernels 1 & 3
    proj_kernel<<<2500, 256, 0, stream>>>(be, Wp, SPb);
    cvt_kernel<<<2500, 256, 0, stream>>>(be, beb);   // 640,000 threads x 4 = 2,560,000
    attn_kernel<<<2500, 256, 0, stream>>>(anc, mask, bias, Ww, SPb, beb, out);
}

// Round 2
// 56.761 us; speedup vs baseline: 1.6832x; 1.6832x over previous
//
#include <hip/hip_runtime.h>
#include <hip/hip_bf16.h>

// Problem constants (N, M, D, A) = (10000, 32, 256, 128)
#define NROW 10000
#define MANC 32
#define DIM  256
#define ADIM 128

typedef __attribute__((ext_vector_type(8))) short short8;
typedef __attribute__((ext_vector_type(4))) short short4v;
typedef __attribute__((ext_vector_type(4))) float floatx4;

__device__ __forceinline__ short f2bf(float x) {
    union { __hip_bfloat16 h; short s; } u;
    u.h = __float2bfloat16(x);
    return u.s;
}
__device__ __forceinline__ float bf2f(unsigned short u) {
    unsigned int x = ((unsigned int)u) << 16;
    return __uint_as_float(x);
}

// ---------------------------------------------------------------------------
// Kernel 1: convert be (10000x256 f32) -> bf16, and build W2bf[256][256] bf16:
//   row j<128:  Wp[j][0:256]      (Wp_self row j)
//   row j>=128: Wp[j-128][256:512] (Wp_anc row j-128)
// 656384 threads x 4 elems. Grid 2564 x 256 exactly.
// ---------------------------------------------------------------------------
__global__ __launch_bounds__(256) void cvt_kernel(
    const float* __restrict__ be, const float* __restrict__ Wp,
    __hip_bfloat16* __restrict__ beb, __hip_bfloat16* __restrict__ w2b) {
    int tid = blockIdx.x * 256 + threadIdx.x;
    const float* src;
    short* dst;
    if (tid < 640000) {
        int base = tid * 4;
        src = be + base;
        dst = reinterpret_cast<short*>(beb) + base;
    } else {
        int base = (tid - 640000) * 4;      // 0 .. 65532
        int j = base >> 8;                  // 0 .. 255
        int k = base & 255;
        src = (j < ADIM) ? (Wp + j * (2 * DIM) + k)
                         : (Wp + (j - ADIM) * (2 * DIM) + DIM + k);
        dst = reinterpret_cast<short*>(w2b) + base;
    }
    floatx4 v = *reinterpret_cast<const floatx4*>(src);
    short4v s;
#pragma unroll
    for (int e = 0; e < 4; ++e) s[e] = f2bf(v[e]);
    *reinterpret_cast<short4v*>(dst) = s;
}

// ---------------------------------------------------------------------------
// Kernel 2: SP[n][j] = beb[n] . W2bf[j]  (bf16 MFMA GEMM, 10000x256, K=256)
// One wave computes 16 rows x 64 cols (4 tiles) so the A-frag is reused 4x.
// 2500 waves = 625 blocks x 256.
// ---------------------------------------------------------------------------
__global__ __launch_bounds__(256) void proj_kernel(
    const __hip_bfloat16* __restrict__ beb, const __hip_bfloat16* __restrict__ w2b,
    __hip_bfloat16* __restrict__ SP) {
    int wid = (blockIdx.x << 2) + (threadIdx.x >> 6);   // 0..2499
    int l   = threadIdx.x & 63;
    int tm  = wid >> 2;          // 0..624  (row tile)
    int q   = wid & 3;           // 0..3    (column quarter: cols q*64 .. q*64+63)
    int kc  = (l >> 4) * 8;

    const unsigned short* A = reinterpret_cast<const unsigned short*>(beb)
                              + (size_t)(tm * 16 + (l & 15)) * DIM;
    const unsigned short* B = reinterpret_cast<const unsigned short*>(w2b);
    int c0 = q * 64 + (l & 15);

    floatx4 acc[4] = {{0,0,0,0},{0,0,0,0},{0,0,0,0},{0,0,0,0}};
#pragma unroll
    for (int k0 = 0; k0 < DIM; k0 += 32) {
        short8 av = *reinterpret_cast<const short8*>(A + k0 + kc);
#pragma unroll
        for (int t = 0; t < 4; ++t) {
            short8 bv = *reinterpret_cast<const short8*>(
                B + (size_t)(c0 + t * 16) * DIM + k0 + kc);
            acc[t] = __builtin_amdgcn_mfma_f32_16x16x32_bf16(av, bv, acc[t], 0, 0, 0);
        }
    }
    // C/D layout: col = lane&15, row = (lane>>4)*4 + r
    int orow = tm * 16 + ((l >> 4) << 2);
#pragma unroll
    for (int t = 0; t < 4; ++t) {
#pragma unroll
        for (int r = 0; r < 4; ++r) {
            union { __hip_bfloat16 h; short s; } u;
            u.s = f2bf(acc[t][r]);
            SP[(size_t)(orow + r) * DIM + q * 64 + t * 16 + (l & 15)] = u.h;
        }
    }
}

// ---------------------------------------------------------------------------
// Kernel 3: attention. One wave per row n.
// Phase 1: scores via MFMA. A-frag rows = ancestor m (lane&15 picks m within a
//   16-tile, two tiles for m=0..31); k = the ADIM=128 attention dim; tanh is
//   computed elementwise into the A-fragment. B-frag = Ww in column 0 only.
//   C col 0 => lanes {0,16,32,48} hold scores for rows (lane>>4)*4 + r.
// Phase 2: softmax in holder lanes (shfl_xor 16/32), weights broadcast by
//   v_readlane, weighted E-gather sum (lane owns 4 of the 256 d's).
// ---------------------------------------------------------------------------
__global__ __launch_bounds__(256) void attn_kernel(
    const int*   __restrict__ anc,
    const float* __restrict__ mask,
    const float* __restrict__ bias,
    const float* __restrict__ Ww,
    const __hip_bfloat16* __restrict__ SP,
    const __hip_bfloat16* __restrict__ beb,
    float* __restrict__ out) {
    int tid = blockIdx.x * 256 + threadIdx.x;
    int l   = tid & 63;
    int n   = __builtin_amdgcn_readfirstlane(tid >> 6);   // wave-uniform row
    int kc  = (l >> 4) * 8;

    const unsigned short* SPu = reinterpret_cast<const unsigned short*>(SP);

    // ssb[kt][i] = self_proj[n][a] + bias[a],  a = kt*32 + kc + i
    float ssb[4][8];
#pragma unroll
    for (int kt = 0; kt < 4; ++kt) {
        short8 sv = *reinterpret_cast<const short8*>(SPu + (size_t)n * DIM + kt * 32 + kc);
        floatx4 b0 = *reinterpret_cast<const floatx4*>(bias + kt * 32 + kc);
        floatx4 b1 = *reinterpret_cast<const floatx4*>(bias + kt * 32 + kc + 4);
#pragma unroll
        for (int i = 0; i < 8; ++i)
            ssb[kt][i] = bf2f((unsigned short)sv[i]) + ((i < 4) ? b0[i & 3] : b1[i & 3]);
    }

    // B-frag: B[k][c] = (c==0) ? Ww[k] : 0
    float keep = ((l & 15) == 0) ? 1.f : 0.f;
    short8 bw[4];
#pragma unroll
    for (int kt = 0; kt < 4; ++kt) {
        floatx4 w0 = *reinterpret_cast<const floatx4*>(Ww + kt * 32 + kc);
        floatx4 w1 = *reinterpret_cast<const floatx4*>(Ww + kt * 32 + kc + 4);
#pragma unroll
        for (int i = 0; i < 8; ++i)
            bw[kt][i] = f2bf(((i < 4) ? w0[i & 3] : w1[i & 3]) * keep);
    }

    int m0 = l & 15;
    int j0 = anc[n * MANC + m0];
    int j1 = anc[n * MANC + 16 + m0];

    floatx4 acc0 = {0,0,0,0}, acc1 = {0,0,0,0};
#pragma unroll
    for (int kt = 0; kt < 4; ++kt) {
        short8 pv = *reinterpret_cast<const short8*>(
            SPu + (size_t)j0 * DIM + ADIM + kt * 32 + kc);
        short8 af;
#pragma unroll
        for (int i = 0; i < 8; ++i) {
            float x  = ssb[kt][i] + bf2f((unsigned short)pv[i]);
            float x2 = __builtin_amdgcn_fmed3f(x + x, -16.f, 16.f);
            float e  = __expf(x2);
            af[i]    = f2bf((e - 1.f) * __builtin_amdgcn_rcpf(e + 1.f));
        }
        acc0 = __builtin_amdgcn_mfma_f32_16x16x32_bf16(af, bw[kt], acc0, 0, 0, 0);
    }
#pragma unroll
    for (int kt = 0; kt < 4; ++kt) {
        short8 pv = *reinterpret_cast<const short8*>(
            SPu + (size_t)j1 * DIM + ADIM + kt * 32 + kc);
        short8 af;
#pragma unroll
        for (int i = 0; i < 8; ++i) {
            float x  = ssb[kt][i] + bf2f((unsigned short)pv[i]);
            float x2 = __builtin_amdgcn_fmed3f(x + x, -16.f, 16.f);
            float e  = __expf(x2);
            af[i]    = f2bf((e - 1.f) * __builtin_amdgcn_rcpf(e + 1.f));
        }
        acc1 = __builtin_amdgcn_mfma_f32_16x16x32_bf16(af, bw[kt], acc1, 0, 0, 0);
    }

    // scores live in lanes with (l&15)==0: rows rb..rb+3 (tile0), 16+rb.. (tile1)
    int rb = (l >> 4) << 2;
    float s0[4], s1[4];
#pragma unroll
    for (int r = 0; r < 4; ++r) {
        s0[r] = acc0[r] * mask[n * MANC + rb + r];
        s1[r] = acc1[r] * mask[n * MANC + 16 + rb + r];
    }
    float mx = s0[0];
#pragma unroll
    for (int r = 0; r < 4; ++r) { mx = fmaxf(mx, s0[r]); mx = fmaxf(mx, s1[r]); }
    mx = fmaxf(mx, __shfl_xor(mx, 16, 64));
    mx = fmaxf(mx, __shfl_xor(mx, 32, 64));
    float wn0[4], wn1[4], tot = 0.f;
#pragma unroll
    for (int r = 0; r < 4; ++r) {
        wn0[r] = __expf(s0[r] - mx); tot += wn0[r];
        wn1[r] = __expf(s1[r] - mx); tot += wn1[r];
    }
    tot += __shfl_xor(tot, 16, 64);
    tot += __shfl_xor(tot, 32, 64);
    float inv = __builtin_amdgcn_rcpf(tot);
#pragma unroll
    for (int r = 0; r < 4; ++r) { wn0[r] *= inv; wn1[r] *= inv; }

    // Phase 2: G[n] = sum_m wn[m] * E[j_m];  lane owns d = 4l..4l+3
    const unsigned short* bebu = reinterpret_cast<const unsigned short*>(beb);
    floatx4 acc = {0,0,0,0};
#pragma unroll
    for (int m = 0; m < MANC; ++m) {
        int src = ((m & 15) >> 2) << 4;   // holder lane of row m (col-0 lanes)
        float wm = (m < 16) ? __shfl(wn0[m & 3], src, 64)
                            : __shfl(wn1[m & 3], src, 64);
        int j = anc[n * MANC + m];
        short4v ev = *reinterpret_cast<const short4v*>(bebu + (size_t)j * DIM + l * 4);
#pragma unroll
        for (int e = 0; e < 4; ++e) acc[e] += wm * bf2f((unsigned short)ev[e]);
    }
    *reinterpret_cast<floatx4*>(out + (size_t)n * DIM + l * 4) = acc;
}

// ---------------------------------------------------------------------------
extern "C" void kernel_launch(void* const* d_in, const int* in_sizes, int n_in,
                              void* d_out, int out_size, void* d_ws, size_t ws_size,
                              hipStream_t stream) {
    const float* be   = (const float*)d_in[0];
    const int*   anc  = (const int*)d_in[1];
    const float* mask = (const float*)d_in[2];
    const float* Wp   = (const float*)d_in[3];
    const float* bias = (const float*)d_in[4];
    const float* Ww   = (const float*)d_in[5];
    float* out = (float*)d_out;

    // ws: [0,5.12M) SP bf16 | [5.12M,10.24M) beb bf16 | [10.24M,+128K) W2 bf16
    __hip_bfloat16* SPb = (__hip_bfloat16*)d_ws;
    __hip_bfloat16* beb = (__hip_bfloat16*)((char*)d_ws + (size_t)NROW * DIM * 2);
    __hip_bfloat16* w2b = (__hip_bfloat16*)((char*)d_ws + (size_t)2 * NROW * DIM * 2);

    cvt_kernel<<<2564, 256, 0, stream>>>(be, Wp, beb, w2b);
    proj_kernel<<<625, 256, 0, stream>>>(beb, w2b, SPb);
    attn_kernel<<<2500, 256, 0, stream>>>(anc, mask, bias, Ww, SPb, beb, out);
}

// Round 4
// 46.690 us; speedup vs baseline: 2.0463x; 1.2157x over previous
//
#include <hip/hip_runtime.h>
#include <hip/hip_bf16.h>

// Problem constants (N, M, D, A) = (10000, 32, 256, 128)
#define NROW 10000
#define MANC 32
#define DIM  256
#define ADIM 128

typedef __attribute__((ext_vector_type(8))) short short8;
typedef __attribute__((ext_vector_type(4))) short short4v;
typedef __attribute__((ext_vector_type(4))) float floatx4;
typedef __attribute__((ext_vector_type(2))) unsigned int uint2v;

#if __has_builtin(__builtin_amdgcn_exp2f)
#define EXP2F(x) __builtin_amdgcn_exp2f(x)
#else
#define EXP2F(x) __expf((x) * 0.69314718055994531f)
#endif

#define C2L2E 2.8853900817779268f   // 2*log2(e)
#define L2E   1.4426950408889634f   // log2(e)

static __device__ __forceinline__ short f2bf(float x) {
    union { __hip_bfloat16 h; short s; } u;
    u.h = __float2bfloat16(x);
    return u.s;
}
static __device__ __forceinline__ float bf2f(unsigned short u) {
    return __uint_as_float(((unsigned int)u) << 16);
}

// ---------------------------------------------------------------------------
// proj: SP[n][j] = be[n] . W2[j]  (W2 row j<128 = Wp_self row j, j>=128 =
// Wp_anc row j-128).  Block = 4 waves = 64 rows x 64-col quarter.
// W-quarter staged f32->bf16 into XOR-swizzled LDS; A read f32 + inline cvt.
// q==0 blocks also emit beb (bf16 copy of be) as a side product.
// Grid: 157 row-blocks x 4 quarters = 628 blocks.
// ---------------------------------------------------------------------------
__global__ __launch_bounds__(256) void proj_kernel(
    const float* __restrict__ be, const float* __restrict__ Wp,
    __hip_bfloat16* __restrict__ SP, __hip_bfloat16* __restrict__ beb) {
    __shared__ short lds[64 * 256];          // 32 KB: 64 W2-rows x 256 k (bf16)
    int q  = blockIdx.x & 3;                 // col quarter
    int rb = blockIdx.x >> 2;                // row block 0..156
    int t  = threadIdx.x;

    // ---- stage W quarter: rows j = q*64 .. q*64+63 ----
#pragma unroll
    for (int i = 0; i < 8; ++i) {
        int c  = i * 256 + t;                // 16B chunk id 0..2047
        int jl = c >> 5;                     // local row 0..63
        int e0 = (c & 31) * 8;               // elem offset 0..248
        int j  = q * 64 + jl;
        const float* src = (j < ADIM) ? (Wp + (size_t)j * (2 * DIM) + e0)
                                      : (Wp + (size_t)(j - ADIM) * (2 * DIM) + DIM + e0);
        floatx4 v0 = *(const floatx4*)src;
        floatx4 v1 = *(const floatx4*)(src + 4);
        short8 s;
#pragma unroll
        for (int e = 0; e < 4; ++e) { s[e] = f2bf(v0[e]); s[4 + e] = f2bf(v1[e]); }
        int byte = (c * 16) ^ ((jl & 7) << 4);   // involutive swizzle
        *(short8*)((char*)lds + byte) = s;
    }
    __syncthreads();

    int w    = t >> 6;
    int l    = t & 63;
    int tm   = rb * 4 + w;                   // row tile 0..627
    int arow = tm * 16 + (l & 15);
    int rcl  = min(arow, NROW - 1);
    int kc   = (l >> 4) * 8;
    const float* A = be + (size_t)rcl * DIM;

    floatx4 acc[4] = {{0,0,0,0},{0,0,0,0},{0,0,0,0},{0,0,0,0}};
#pragma unroll
    for (int k0 = 0; k0 < DIM; k0 += 32) {
        floatx4 a0 = *(const floatx4*)(A + k0 + kc);
        floatx4 a1 = *(const floatx4*)(A + k0 + kc + 4);
        short8 av;
#pragma unroll
        for (int e = 0; e < 4; ++e) { av[e] = f2bf(a0[e]); av[4 + e] = f2bf(a1[e]); }
        if (q == 0 && arow < NROW)
            *(short8*)((unsigned short*)beb + (size_t)arow * DIM + k0 + kc) = av;
#pragma unroll
        for (int tt = 0; tt < 4; ++tt) {
            int jl   = tt * 16 + (l & 15);
            int byte = (jl * 512 + (k0 + kc) * 2) ^ ((jl & 7) << 4);
            short8 bv = *(const short8*)((char*)lds + byte);
            acc[tt] = __builtin_amdgcn_mfma_f32_16x16x32_bf16(av, bv, acc[tt], 0, 0, 0);
        }
    }
    // C/D layout: col = lane&15, row = (lane>>4)*4 + r
    int orow = tm * 16 + ((l >> 4) << 2);
#pragma unroll
    for (int tt = 0; tt < 4; ++tt) {
#pragma unroll
        for (int r = 0; r < 4; ++r) {
            if (orow + r < NROW) {
                union { __hip_bfloat16 h; short s; } u;
                u.s = f2bf(acc[tt][r]);
                SP[(size_t)(orow + r) * DIM + q * 64 + tt * 16 + (l & 15)] = u.h;
            }
        }
    }
}

// ---------------------------------------------------------------------------
// attn helper: one 16-ancestor score tile via tanh + MFMA (scores in col 0).
// ---------------------------------------------------------------------------
static __device__ __forceinline__ floatx4 score_tile(
    const unsigned short* __restrict__ SPu, int j, int kc,
    const float (&ssby)[4][8], const short8 (&bw)[4], floatx4 acc) {
    const unsigned short* p = SPu + (size_t)j * DIM + ADIM + kc;
#pragma unroll
    for (int kt = 0; kt < 4; ++kt) {
        short8 pv = *(const short8*)(p + kt * 32);
        short8 af;
#pragma unroll
        for (int i = 0; i < 8; ++i) {
            float y = fmaf(bf2f((unsigned short)pv[i]), C2L2E, ssby[kt][i]);
            y = __builtin_amdgcn_fmed3f(y, -28.f, 28.f);
            float e = EXP2F(y);                        // e = exp(2x)
            float r = __builtin_amdgcn_rcpf(e + 1.f);
            af[i] = f2bf(fmaf(-2.f, r, 1.f));          // tanh(x)
        }
        acc = __builtin_amdgcn_mfma_f32_16x16x32_bf16(af, bw[kt], acc, 0, 0, 0);
    }
    return acc;
}

// ---------------------------------------------------------------------------
// attn: one wave per row n. Scores via MFMA (Ww in B column 0), softmax in
// the 4 col-0 holder lanes, weighted E-gather sum (lane owns d = 4l..4l+3).
// Tile 1 (m=16..31) skipped wave-uniformly when mask[n][16]==0.
// FIX vs r3: broadcast reduced denominator from holder lane 0 to all lanes
// (non-holder lanes' locally-reduced tot is garbage; r3 scaled 60/64 of the
// output by a wrong factor).
// ---------------------------------------------------------------------------
__global__ __launch_bounds__(256) void attn_kernel(
    const int*   __restrict__ anc,
    const float* __restrict__ mask,
    const float* __restrict__ bias,
    const float* __restrict__ Ww,
    const __hip_bfloat16* __restrict__ SP,
    const __hip_bfloat16* __restrict__ beb,
    float* __restrict__ out) {
    int tid = blockIdx.x * 256 + threadIdx.x;
    int l   = tid & 63;
    int n   = __builtin_amdgcn_readfirstlane(tid >> 6);
    int kc  = (l >> 4) * 8;
    const unsigned short* SPu = (const unsigned short*)SP;

    // ssby[kt][i] = 2*log2e * (self_proj[n][a] + bias[a]),  a = kt*32+kc+i
    float ssby[4][8];
#pragma unroll
    for (int kt = 0; kt < 4; ++kt) {
        short8 sv = *(const short8*)(SPu + (size_t)n * DIM + kt * 32 + kc);
        floatx4 b0 = *(const floatx4*)(bias + kt * 32 + kc);
        floatx4 b1 = *(const floatx4*)(bias + kt * 32 + kc + 4);
#pragma unroll
        for (int i = 0; i < 8; ++i)
            ssby[kt][i] = (bf2f((unsigned short)sv[i]) + ((i < 4) ? b0[i & 3] : b1[i & 3])) * C2L2E;
    }

    // B-frag: B[k][c] = (c==0) ? Ww[k] : 0
    float keep = ((l & 15) == 0) ? 1.f : 0.f;
    short8 bw[4];
#pragma unroll
    for (int kt = 0; kt < 4; ++kt) {
        floatx4 w0 = *(const floatx4*)(Ww + kt * 32 + kc);
        floatx4 w1 = *(const floatx4*)(Ww + kt * 32 + kc + 4);
#pragma unroll
        for (int i = 0; i < 8; ++i)
            bw[kt][i] = f2bf(((i < 4) ? w0[i & 3] : w1[i & 3]) * keep);
    }

    const int*   ancn = anc  + n * MANC;
    const float* mrow = mask + n * MANC;
    bool has2 = mrow[16] != 0.f;             // wave-uniform: any of m=16..31 live?

    int m0 = l & 15;
    floatx4 acc0 = {0,0,0,0}, acc1 = {0,0,0,0};
    acc0 = score_tile(SPu, ancn[m0], kc, ssby, bw, acc0);
    if (has2)
        acc1 = score_tile(SPu, ancn[16 + m0], kc, ssby, bw, acc1);

    // scores in lanes (l&15)==0: rows rb..rb+3 (tile0), 16+rb..16+rb+3 (tile1)
    int rb = (l >> 4) << 2;
    float s0[4], s1[4];
#pragma unroll
    for (int r = 0; r < 4; ++r) {
        s0[r] = acc0[r] * mrow[rb + r];
        s1[r] = acc1[r] * mrow[16 + rb + r];
    }
    float mx = s0[0];
#pragma unroll
    for (int r = 0; r < 4; ++r) { mx = fmaxf(mx, s0[r]); mx = fmaxf(mx, s1[r]); }
    mx = fmaxf(mx, __shfl_xor(mx, 16, 64));
    mx = fmaxf(mx, __shfl_xor(mx, 32, 64));
    float nm = -mx * L2E;
    float wn0[4], wn1[4], tot = 0.f;
#pragma unroll
    for (int r = 0; r < 4; ++r) {
        wn0[r] = EXP2F(fmaf(s0[r], L2E, nm)); tot += wn0[r];
        wn1[r] = EXP2F(fmaf(s1[r], L2E, nm)); tot += wn1[r];
    }
    tot += __shfl_xor(tot, 16, 64);
    tot += __shfl_xor(tot, 32, 64);
    tot = __shfl(tot, 0, 64);                // FIX: lane 0 holds the true sum
    float inv = __builtin_amdgcn_rcpf(tot);

    // Phase 2: G[n] = (sum_m wn[m] * E[j_m]) * inv;  lane owns d = 4l..4l+3
    const unsigned short* ebase = (const unsigned short*)beb + (size_t)l * 4;
    float a0 = 0.f, a1 = 0.f, a2 = 0.f, a3 = 0.f;
#pragma unroll
    for (int m = 0; m < MANC; ++m) {
        int src = ((m & 15) >> 2) << 4;      // holder lane of row m
        float wm = (m < 16) ? __shfl(wn0[m & 3], src, 64)
                            : __shfl(wn1[m & 3], src, 64);
        uint2v dv = *(const uint2v*)(ebase + (size_t)ancn[m] * DIM);
        a0 = fmaf(wm, __uint_as_float(dv.x << 16),          a0);
        a1 = fmaf(wm, __uint_as_float(dv.x & 0xffff0000u),  a1);
        a2 = fmaf(wm, __uint_as_float(dv.y << 16),          a2);
        a3 = fmaf(wm, __uint_as_float(dv.y & 0xffff0000u),  a3);
    }
    floatx4 res = {a0 * inv, a1 * inv, a2 * inv, a3 * inv};
    *(floatx4*)(out + (size_t)n * DIM + l * 4) = res;
}

// ---------------------------------------------------------------------------
extern "C" void kernel_launch(void* const* d_in, const int* in_sizes, int n_in,
                              void* d_out, int out_size, void* d_ws, size_t ws_size,
                              hipStream_t stream) {
    const float* be   = (const float*)d_in[0];
    const int*   anc  = (const int*)d_in[1];
    const float* mask = (const float*)d_in[2];
    const float* Wp   = (const float*)d_in[3];
    const float* bias = (const float*)d_in[4];
    const float* Ww   = (const float*)d_in[5];
    float* out = (float*)d_out;

    // ws: [0, 5.12M) SP bf16 | [5.12M, 10.24M) beb bf16
    __hip_bfloat16* SPb = (__hip_bfloat16*)d_ws;
    __hip_bfloat16* beb = (__hip_bfloat16*)((char*)d_ws + (size_t)NROW * DIM * 2);

    proj_kernel<<<628, 256, 0, stream>>>(be, Wp, SPb, beb);
    attn_kernel<<<2500, 256, 0, stream>>>(anc, mask, bias, Ww, SPb, beb, out);
}